// Round 10
// baseline (4983.087 us; speedup 1.0000x reference)
//
#include <hip/hip_runtime.h>
#include <stdint.h>

#define TSEQ  784
#define BATCH 256
#define HID   256
#define DNS   1024
#define NCLS  10
#define NGRP  16   // groups (16 batch rows each)
#define NSLC  8    // slices (32 units x 4 gates = 128 gate-cols each)

typedef __attribute__((ext_vector_type(8))) short bf16x8_t;
typedef __attribute__((ext_vector_type(4))) float f32x4_t;

__device__ __forceinline__ float sigmoidf_(float x) { return 1.0f / (1.0f + __expf(-x)); }
__device__ __forceinline__ float tanhf_(float x) {
    float ax = fabsf(x);
    float e  = __expf(2.0f * ax);
    float r  = 1.0f - 2.0f / (e + 1.0f);
    return copysignf(r, x);
}
__device__ __forceinline__ uint32_t bf16rne(float f) {
    uint32_t u = __float_as_uint(f);
    return (u + 0x7FFFu + ((u >> 16) & 1u)) >> 16;
}
__device__ __forceinline__ float bf16tof(uint32_t h) { return __uint_as_float(h << 16); }

union AF { uint32_t u[4]; unsigned long long q[2]; bf16x8_t v; };

#define ALOAD(dst, ptr) \
    dst = __hip_atomic_load((ptr), __ATOMIC_RELAXED, __HIP_MEMORY_SCOPE_AGENT)

// 64 blocks = 8 pairs x 8 slices, 256 threads (4 waves).
// Each block advances TWO batch groups (gA=2p, gB=2p+1) per iteration with a
// single poll/drain/tag exchange: per-step sync cost halves. B-fragments are
// read from LDS once per k-tile and feed both groups' MFMAs. A-fragments are
// loaded directly from global hx (layout == A-frag order, proven in round 8).
__global__ __launch_bounds__(256, 1)
void lstm_mfma2(const float* __restrict__ X,
                const float* __restrict__ W_lstm,
                const float* __restrict__ b_lstm,
                uint32_t* __restrict__ hx,      // 2 bufs * 16 g * 8 s * 512 dwords
                uint32_t* __restrict__ tags)    // 128 monotonic tags [g*8+s]
{
    __shared__ uint32_t WtU[32768];           // 128 KB weights bf16 hi/lo, swizzled
    __shared__ float    gateA[4 * 32 * 17];   // 8.5 KB gates group A [q][col][row+pad]
    __shared__ float    gateB[4 * 32 * 17];   // 8.5 KB gates group B

    const int tid  = threadIdx.x;
    const int lane = tid & 63;
    const int wid  = tid >> 6;    // 0..3 == gate q owned by this wave
    const int cidx = lane & 15;   // B col / A row within tile
    const int kh   = lane >> 4;   // 0..3 k-subgroup

    const int bid = blockIdx.x;   // 64 blocks
    const int s   = bid >> 3;     // slice 0..7
    const int p   = bid & 7;      // pair 0..7 (all slices of a pair share bid%8 -> XCD)
    const int gA  = 2 * p, gB = 2 * p + 1;

    // ---- one-time: stage Wh slice into LDS as bf16 hi/lo, chunk-XOR-swizzled ----
    for (int idx = tid; idx < 8 * 16 * 128; idx += 256) {
        const int n  = idx >> 11;          // n-tile 0..7
        const int c  = (idx >> 7) & 15;    // col within tile
        const int dw = idx & 127;          // k-pair index
        const int k0 = dw * 2;
        const int col = (n >> 1) * 256 + s * 32 + (n & 1) * 16 + c;
        const float w0 = W_lstm[(1 + k0) * 1024 + col];
        const float w1 = W_lstm[(2 + k0) * 1024 + col];
        const uint32_t h0 = bf16rne(w0), h1 = bf16rne(w1);
        const uint32_t l0 = bf16rne(w0 - bf16tof(h0));
        const uint32_t l1 = bf16rne(w1 - bf16tof(h1));
        const int kc = dw >> 2, rem = dw & 3;
        const int dwp = ((kc ^ (c & 7)) << 2) | rem;
        const int o = (n * 16 + c) * 128 + dwp;
        WtU[o]         = h0 | (h1 << 16);
        WtU[16384 + o] = l0 | (l1 << 16);
    }

    // eltwise mapping: thread -> (row er, unit eu); cells (er,eu),(er,eu+16)
    const int er = tid >> 4;
    const int eu = tid & 15;
    float wx0[4], wx1[4], bb0[4], bb1[4];
    #pragma unroll
    for (int q = 0; q < 4; ++q) {
        const int c0 = q * 256 + s * 32 + eu;
        wx0[q] = W_lstm[c0];      wx1[q] = W_lstm[c0 + 16];
        bb0[q] = b_lstm[c0];      bb1[q] = b_lstm[c0 + 16];
    }
    const float* xrowA = X + (gA * 16 + er) * TSEQ;
    const float* xrowB = X + (gB * 16 + er) * TSEQ;
    float ccA0 = 0.f, ccA1 = 0.f, ccB0 = 0.f, ccB1 = 0.f;

    __syncthreads();

    for (int t = 0; t < TSEQ; ++t) {
        // ---- wave 0 polls all 16 producer tags (both groups) >= t ----
        if (t > 0 && wid == 0) {
            const uint32_t tt = (uint32_t)t;
            int guard = 1 << 22;
            bool ok;
            do {
                uint32_t v = __hip_atomic_load(&tags[p * 16 + (lane & 15)],
                                               __ATOMIC_RELAXED, __HIP_MEMORY_SCOPE_AGENT);
                ok = __all(v >= tt);
            } while (!ok && --guard);
        }
        __syncthreads();   // join + fence: A-loads cannot hoist above poll

        // ---- A-fragments for both groups, direct from global (coalesced u64) ----
        const int bufr = t & 1;
        AF ahA[8], alA[8], ahB[8], alB[8];
        #pragma unroll
        for (int kt = 0; kt < 8; ++kt) {
            const int baseA = ((bufr * NGRP + gA) * NSLC + kt) * 512 + cidx * 16 + kh * 4;
            const int baseB = ((bufr * NGRP + gB) * NSLC + kt) * 512 + cidx * 16 + kh * 4;
            const unsigned long long* pa = (const unsigned long long*)&hx[baseA];
            const unsigned long long* pb = (const unsigned long long*)&hx[baseB];
            ALOAD(ahA[kt].q[0], pa);       ALOAD(ahA[kt].q[1], pa + 1);
            ALOAD(alA[kt].q[0], pa + 128); ALOAD(alA[kt].q[1], pa + 129);
            ALOAD(ahB[kt].q[0], pb);       ALOAD(ahB[kt].q[1], pb + 1);
            ALOAD(alB[kt].q[0], pb + 128); ALOAD(alB[kt].q[1], pb + 129);
        }

        // ---- GEMM: B-frags read once per kt, feed BOTH groups (3-term split) ----
        f32x4_t aA0 = {0.f, 0.f, 0.f, 0.f}, aA1 = aA0, aB0 = aA0, aB1 = aA0;
        #pragma unroll
        for (int kt = 0; kt < 8; ++kt) {
            const int kc  = kt * 4 + kh;
            const int ob0 = ((wid * 2) * 16 + cidx) * 128 + ((kc ^ (cidx & 7)) << 2);
            const int ob1 = ((wid * 2 + 1) * 16 + cidx) * 128 + ((kc ^ (cidx & 7)) << 2);
            bf16x8_t bh0 = *reinterpret_cast<const bf16x8_t*>(&WtU[ob0]);
            bf16x8_t bl0 = *reinterpret_cast<const bf16x8_t*>(&WtU[16384 + ob0]);
            bf16x8_t bh1 = *reinterpret_cast<const bf16x8_t*>(&WtU[ob1]);
            bf16x8_t bl1 = *reinterpret_cast<const bf16x8_t*>(&WtU[16384 + ob1]);
            aA0 = __builtin_amdgcn_mfma_f32_16x16x32_bf16(ahA[kt].v, bh0, aA0, 0, 0, 0);
            aA0 = __builtin_amdgcn_mfma_f32_16x16x32_bf16(ahA[kt].v, bl0, aA0, 0, 0, 0);
            aA0 = __builtin_amdgcn_mfma_f32_16x16x32_bf16(alA[kt].v, bh0, aA0, 0, 0, 0);
            aA1 = __builtin_amdgcn_mfma_f32_16x16x32_bf16(ahA[kt].v, bh1, aA1, 0, 0, 0);
            aA1 = __builtin_amdgcn_mfma_f32_16x16x32_bf16(ahA[kt].v, bl1, aA1, 0, 0, 0);
            aA1 = __builtin_amdgcn_mfma_f32_16x16x32_bf16(alA[kt].v, bh1, aA1, 0, 0, 0);
            aB0 = __builtin_amdgcn_mfma_f32_16x16x32_bf16(ahB[kt].v, bh0, aB0, 0, 0, 0);
            aB0 = __builtin_amdgcn_mfma_f32_16x16x32_bf16(ahB[kt].v, bl0, aB0, 0, 0, 0);
            aB0 = __builtin_amdgcn_mfma_f32_16x16x32_bf16(alB[kt].v, bh0, aB0, 0, 0, 0);
            aB1 = __builtin_amdgcn_mfma_f32_16x16x32_bf16(ahB[kt].v, bh1, aB1, 0, 0, 0);
            aB1 = __builtin_amdgcn_mfma_f32_16x16x32_bf16(ahB[kt].v, bl1, aB1, 0, 0, 0);
            aB1 = __builtin_amdgcn_mfma_f32_16x16x32_bf16(alB[kt].v, bh1, aB1, 0, 0, 0);
        }

        // ---- scatter gates (D: col=lane&15, row=(lane>>4)*4+reg) ----
        #pragma unroll
        for (int reg = 0; reg < 4; ++reg) {
            gateA[(wid * 32 + cidx) * 17      + kh * 4 + reg] = aA0[reg];
            gateA[(wid * 32 + 16 + cidx) * 17 + kh * 4 + reg] = aA1[reg];
            gateB[(wid * 32 + cidx) * 17      + kh * 4 + reg] = aB0[reg];
            gateB[(wid * 32 + 16 + cidx) * 17 + kh * 4 + reg] = aB1[reg];
        }
        __syncthreads();

        const int bufw = (t + 1) & 1;

        // ---- eltwise + pack + store, group A ----
        {
            const float xv = xrowA[t];
            float g0[4], g1[4];
            #pragma unroll
            for (int q = 0; q < 4; ++q) {
                g0[q] = gateA[(q * 32 + eu) * 17 + er]      + xv * wx0[q] + bb0[q];
                g1[q] = gateA[(q * 32 + 16 + eu) * 17 + er] + xv * wx1[q] + bb1[q];
            }
            ccA0 = fmaf(sigmoidf_(g0[2] + 1.0f), ccA0, sigmoidf_(g0[0]) * tanhf_(g0[1]));
            const float h0 = sigmoidf_(g0[3]) * tanhf_(ccA0);
            ccA1 = fmaf(sigmoidf_(g1[2] + 1.0f), ccA1, sigmoidf_(g1[0]) * tanhf_(g1[1]));
            const float h1 = sigmoidf_(g1[3]) * tanhf_(ccA1);
            const float h0n = __shfl_xor(h0, 1, 64);
            const float h1n = __shfl_xor(h1, 1, 64);
            if ((eu & 1) == 0) {
                const int basew = ((bufw * NGRP + gA) * NSLC + s) * 512 + er * 16;
                const uint32_t hi0 = bf16rne(h0),  hi0n = bf16rne(h0n);
                const uint32_t hi1 = bf16rne(h1),  hi1n = bf16rne(h1n);
                const uint32_t lo0  = bf16rne(h0  - bf16tof(hi0));
                const uint32_t lo0n = bf16rne(h0n - bf16tof(hi0n));
                const uint32_t lo1  = bf16rne(h1  - bf16tof(hi1));
                const uint32_t lo1n = bf16rne(h1n - bf16tof(hi1n));
                const int D0 = eu >> 1, D1 = 8 + (eu >> 1);
                __hip_atomic_store(&hx[basew + D0], hi0 | (hi0n << 16),
                                   __ATOMIC_RELAXED, __HIP_MEMORY_SCOPE_AGENT);
                __hip_atomic_store(&hx[basew + D1], hi1 | (hi1n << 16),
                                   __ATOMIC_RELAXED, __HIP_MEMORY_SCOPE_AGENT);
                __hip_atomic_store(&hx[basew + 256 + D0], lo0 | (lo0n << 16),
                                   __ATOMIC_RELAXED, __HIP_MEMORY_SCOPE_AGENT);
                __hip_atomic_store(&hx[basew + 256 + D1], lo1 | (lo1n << 16),
                                   __ATOMIC_RELAXED, __HIP_MEMORY_SCOPE_AGENT);
            }
        }
        // ---- eltwise + pack + store, group B ----
        {
            const float xv = xrowB[t];
            float g0[4], g1[4];
            #pragma unroll
            for (int q = 0; q < 4; ++q) {
                g0[q] = gateB[(q * 32 + eu) * 17 + er]      + xv * wx0[q] + bb0[q];
                g1[q] = gateB[(q * 32 + 16 + eu) * 17 + er] + xv * wx1[q] + bb1[q];
            }
            ccB0 = fmaf(sigmoidf_(g0[2] + 1.0f), ccB0, sigmoidf_(g0[0]) * tanhf_(g0[1]));
            const float h0 = sigmoidf_(g0[3]) * tanhf_(ccB0);
            ccB1 = fmaf(sigmoidf_(g1[2] + 1.0f), ccB1, sigmoidf_(g1[0]) * tanhf_(g1[1]));
            const float h1 = sigmoidf_(g1[3]) * tanhf_(ccB1);
            const float h0n = __shfl_xor(h0, 1, 64);
            const float h1n = __shfl_xor(h1, 1, 64);
            if ((eu & 1) == 0) {
                const int basew = ((bufw * NGRP + gB) * NSLC + s) * 512 + er * 16;
                const uint32_t hi0 = bf16rne(h0),  hi0n = bf16rne(h0n);
                const uint32_t hi1 = bf16rne(h1),  hi1n = bf16rne(h1n);
                const uint32_t lo0  = bf16rne(h0  - bf16tof(hi0));
                const uint32_t lo0n = bf16rne(h0n - bf16tof(hi0n));
                const uint32_t lo1  = bf16rne(h1  - bf16tof(hi1));
                const uint32_t lo1n = bf16rne(h1n - bf16tof(hi1n));
                const int D0 = eu >> 1, D1 = 8 + (eu >> 1);
                __hip_atomic_store(&hx[basew + D0], hi0 | (hi0n << 16),
                                   __ATOMIC_RELAXED, __HIP_MEMORY_SCOPE_AGENT);
                __hip_atomic_store(&hx[basew + D1], hi1 | (hi1n << 16),
                                   __ATOMIC_RELAXED, __HIP_MEMORY_SCOPE_AGENT);
                __hip_atomic_store(&hx[basew + 256 + D0], lo0 | (lo0n << 16),
                                   __ATOMIC_RELAXED, __HIP_MEMORY_SCOPE_AGENT);
                __hip_atomic_store(&hx[basew + 256 + D1], lo1 | (lo1n << 16),
                                   __ATOMIC_RELAXED, __HIP_MEMORY_SCOPE_AGENT);
            }
        }
        __syncthreads();   // drains vmcnt(0): both groups' stores at coherent point
        if (tid == 0) {
            __hip_atomic_store(&tags[gA * 8 + s], (uint32_t)(t + 1),
                               __ATOMIC_RELAXED, __HIP_MEMORY_SCOPE_AGENT);
            __hip_atomic_store(&tags[gB * 8 + s], (uint32_t)(t + 1),
                               __ATOMIC_RELAXED, __HIP_MEMORY_SCOPE_AGENT);
        }
    }
}

// One block per batch row: dense = relu(h @ W_dense + b); logits = dense @ W_pred + b
__global__ __launch_bounds__(256, 1)
void head_kernel(const uint32_t* __restrict__ hx,
                 const float* __restrict__ W_dense,
                 const float* __restrict__ b_dense,
                 const float* __restrict__ W_pred,
                 const float* __restrict__ b_pred,
                 float* __restrict__ out) {
    __shared__ float hs[HID];
    __shared__ float ds[DNS];
    __shared__ float red[4];

    const int b = blockIdx.x;
    const int g = b >> 4, er = b & 15;
    const int tid = threadIdx.x;

    {   // reconstruct h = hi + lo from buf 0 chunk of (g, slice s)
        const int s  = tid >> 5;
        const int uu = tid & 31;
        const int base = (g * NSLC + s) * 512 + er * 16;
        const uint32_t dh = __hip_atomic_load(&hx[base + (uu >> 1)],
                                              __ATOMIC_RELAXED, __HIP_MEMORY_SCOPE_AGENT);
        const uint32_t dl = __hip_atomic_load(&hx[base + 256 + (uu >> 1)],
                                              __ATOMIC_RELAXED, __HIP_MEMORY_SCOPE_AGENT);
        const int sh = (uu & 1) * 16;
        hs[tid] = bf16tof((dh >> sh) & 0xFFFFu) + bf16tof((dl >> sh) & 0xFFFFu);
    }
    __syncthreads();

    for (int d = tid; d < DNS; d += 256) {
        float acc = b_dense[d];
        for (int k = 0; k < HID; k += 4) {
            float4 h4 = *reinterpret_cast<const float4*>(&hs[k]);
            acc = fmaf(h4.x, W_dense[(k + 0) * DNS + d], acc);
            acc = fmaf(h4.y, W_dense[(k + 1) * DNS + d], acc);
            acc = fmaf(h4.z, W_dense[(k + 2) * DNS + d], acc);
            acc = fmaf(h4.w, W_dense[(k + 3) * DNS + d], acc);
        }
        ds[d] = fmaxf(acc, 0.0f);
    }
    __syncthreads();

    const int wid = tid >> 6, lane = tid & 63;
    for (int c = 0; c < NCLS; ++c) {
        float p = 0.0f;
        for (int k = tid; k < DNS; k += 256) {
            p = fmaf(ds[k], W_pred[k * NCLS + c], p);
        }
        #pragma unroll
        for (int off = 32; off > 0; off >>= 1) {
            p += __shfl_down(p, off, 64);
        }
        if (lane == 0) red[wid] = p;
        __syncthreads();
        if (tid == 0) {
            out[b * NCLS + c] = red[0] + red[1] + red[2] + red[3] + b_pred[c];
        }
        __syncthreads();
    }
}

extern "C" void kernel_launch(void* const* d_in, const int* in_sizes, int n_in,
                              void* d_out, int out_size, void* d_ws, size_t ws_size,
                              hipStream_t stream) {
    const float* X       = (const float*)d_in[0];
    const float* W_lstm  = (const float*)d_in[1];
    const float* b_lstm  = (const float*)d_in[2];
    const float* W_dense = (const float*)d_in[3];
    const float* b_dense = (const float*)d_in[4];
    const float* W_pred  = (const float*)d_in[5];
    const float* b_pred  = (const float*)d_in[6];
    float* out = (float*)d_out;

    uint32_t* hx   = (uint32_t*)d_ws;                 // 131072 dwords = 512 KB
    uint32_t* tags = hx + 131072;                     // 128 dwords

    hipMemsetAsync(hx, 0, NGRP * NSLC * 512 * sizeof(uint32_t), stream);   // h_0 = 0 (buf 0)
    hipMemsetAsync(tags, 0, NGRP * NSLC * sizeof(uint32_t), stream);

    lstm_mfma2<<<NSLC * 8, 256, 0, stream>>>(X, W_lstm, b_lstm, hx, tags);
    head_kernel<<<BATCH, 256, 0, stream>>>(hx, W_dense, b_dense, W_pred, b_pred, out);
}

// Round 11
// 2895.278 us; speedup vs baseline: 1.7211x; 1.7211x over previous
//
#include <hip/hip_runtime.h>
#include <stdint.h>

#define TSEQ  784
#define BATCH 256
#define HID   256
#define DNS   1024
#define NCLS  10
#define NGRP  16   // groups (16 batch rows each)
#define NSLC  8    // slices (32 units x 4 gates = 128 gate-cols each)

typedef __attribute__((ext_vector_type(8))) short bf16x8_t;
typedef __attribute__((ext_vector_type(4))) float f32x4_t;

__device__ __forceinline__ float sigmoidf_(float x) { return 1.0f / (1.0f + __expf(-x)); }
__device__ __forceinline__ float tanhf_(float x) {
    float ax = fabsf(x);
    float e  = __expf(2.0f * ax);
    float r  = 1.0f - 2.0f / (e + 1.0f);
    return copysignf(r, x);
}
__device__ __forceinline__ uint32_t bf16rne(float f) {
    uint32_t u = __float_as_uint(f);
    return (u + 0x7FFFu + ((u >> 16) & 1u)) >> 16;
}
__device__ __forceinline__ float bf16tof(uint32_t h) { return __uint_as_float(h << 16); }

union AF { uint32_t u[4]; unsigned long long q[2]; bf16x8_t v; };

#define ALOAD(dst, ptr) \
    dst = __hip_atomic_load((ptr), __ATOMIC_RELAXED, __HIP_MEMORY_SCOPE_AGENT)

// 128 blocks = 16 groups x 8 slices, 256 threads (4 waves). Round-8 structure,
// hA staging DELETED: A-fragments load directly from global hx (chunk layout
// == A-frag layout, proven since round 8), batched 16 u64/thread so ~32 loads
// stay in flight. 3 barriers/step. One group per block -> no register spill.
__global__ __launch_bounds__(256, 1)
void lstm_mfma3(const float* __restrict__ X,
                const float* __restrict__ W_lstm,
                const float* __restrict__ b_lstm,
                uint32_t* __restrict__ hx,      // 2 bufs * 16 g * 8 s * 512 dwords
                uint32_t* __restrict__ tags)    // 128 monotonic tags [g*8+s]
{
    __shared__ uint32_t WtU[32768];           // 128 KB weights bf16 hi/lo, swizzled
    __shared__ float    gateL[4 * 32 * 17];   // 8.5 KB gates [q][col][row+pad]

    const int tid  = threadIdx.x;
    const int lane = tid & 63;
    const int wid  = tid >> 6;    // 0..3 == gate q owned by this wave
    const int cidx = lane & 15;   // B col / A row within tile
    const int kh   = lane >> 4;   // 0..3 k-subgroup

    const int bid = blockIdx.x;
    const int s   = bid >> 4;     // slice 0..7
    const int g   = bid & 15;     // group 0..15 (all 8 slices share bid%8 -> XCD)

    // ---- one-time: stage Wh slice into LDS as bf16 hi/lo, chunk-XOR-swizzled ----
    for (int idx = tid; idx < 8 * 16 * 128; idx += 256) {
        const int n  = idx >> 11;          // n-tile 0..7
        const int c  = (idx >> 7) & 15;    // col within tile
        const int dw = idx & 127;          // k-pair index
        const int k0 = dw * 2;
        const int col = (n >> 1) * 256 + s * 32 + (n & 1) * 16 + c;
        const float w0 = W_lstm[(1 + k0) * 1024 + col];
        const float w1 = W_lstm[(2 + k0) * 1024 + col];
        const uint32_t h0 = bf16rne(w0), h1 = bf16rne(w1);
        const uint32_t l0 = bf16rne(w0 - bf16tof(h0));
        const uint32_t l1 = bf16rne(w1 - bf16tof(h1));
        const int kc = dw >> 2, rem = dw & 3;
        const int dwp = ((kc ^ (c & 7)) << 2) | rem;
        const int o = (n * 16 + c) * 128 + dwp;
        WtU[o]         = h0 | (h1 << 16);
        WtU[16384 + o] = l0 | (l1 << 16);
    }

    // eltwise mapping: thread -> (row er, unit eu); cells (er,eu),(er,eu+16)
    const int er = tid >> 4;
    const int eu = tid & 15;
    float wx0[4], wx1[4], bb0[4], bb1[4];
    #pragma unroll
    for (int q = 0; q < 4; ++q) {
        const int c0 = q * 256 + s * 32 + eu;
        wx0[q] = W_lstm[c0];      wx1[q] = W_lstm[c0 + 16];
        bb0[q] = b_lstm[c0];      bb1[q] = b_lstm[c0 + 16];
    }
    const float* xrow = X + (g * 16 + er) * TSEQ;
    float cc0 = 0.0f, cc1 = 0.0f;

    __syncthreads();

    for (int t = 0; t < TSEQ; ++t) {
        // ---- wave 0 polls all 8 producer tags >= t ----
        if (t > 0 && wid == 0) {
            const uint32_t tt = (uint32_t)t;
            int guard = 1 << 22;
            bool ok;
            do {
                uint32_t v = __hip_atomic_load(&tags[g * 8 + (lane & 7)],
                                               __ATOMIC_RELAXED, __HIP_MEMORY_SCOPE_AGENT);
                ok = __all(v >= tt);
            } while (!ok && --guard);
        }
        __syncthreads();   // join + fence: A-loads cannot hoist above poll

        // ---- A-fragments (hi+lo, 8 k-tiles) direct from global, batched ----
        const int bufr = t & 1;
        AF ah[8], al[8];
        #pragma unroll
        for (int kt = 0; kt < 8; ++kt) {
            const int base = ((bufr * NGRP + g) * NSLC + kt) * 512 + cidx * 16 + kh * 4;
            const unsigned long long* pa = (const unsigned long long*)&hx[base];
            ALOAD(ah[kt].q[0], pa);       ALOAD(ah[kt].q[1], pa + 1);
            ALOAD(al[kt].q[0], pa + 128); ALOAD(al[kt].q[1], pa + 129);
        }

        // ---- GEMM: 3-term split over 8 k-tiles, 2 n-tiles per wave ----
        f32x4_t acc0 = {0.f, 0.f, 0.f, 0.f}, acc1 = acc0;
        #pragma unroll
        for (int kt = 0; kt < 8; ++kt) {
            const int kc  = kt * 4 + kh;
            const int ob0 = ((wid * 2) * 16 + cidx) * 128 + ((kc ^ (cidx & 7)) << 2);
            const int ob1 = ((wid * 2 + 1) * 16 + cidx) * 128 + ((kc ^ (cidx & 7)) << 2);
            bf16x8_t bh0 = *reinterpret_cast<const bf16x8_t*>(&WtU[ob0]);
            bf16x8_t bl0 = *reinterpret_cast<const bf16x8_t*>(&WtU[16384 + ob0]);
            bf16x8_t bh1 = *reinterpret_cast<const bf16x8_t*>(&WtU[ob1]);
            bf16x8_t bl1 = *reinterpret_cast<const bf16x8_t*>(&WtU[16384 + ob1]);
            acc0 = __builtin_amdgcn_mfma_f32_16x16x32_bf16(ah[kt].v, bh0, acc0, 0, 0, 0);
            acc0 = __builtin_amdgcn_mfma_f32_16x16x32_bf16(ah[kt].v, bl0, acc0, 0, 0, 0);
            acc0 = __builtin_amdgcn_mfma_f32_16x16x32_bf16(al[kt].v, bh0, acc0, 0, 0, 0);
            acc1 = __builtin_amdgcn_mfma_f32_16x16x32_bf16(ah[kt].v, bh1, acc1, 0, 0, 0);
            acc1 = __builtin_amdgcn_mfma_f32_16x16x32_bf16(ah[kt].v, bl1, acc1, 0, 0, 0);
            acc1 = __builtin_amdgcn_mfma_f32_16x16x32_bf16(al[kt].v, bh1, acc1, 0, 0, 0);
        }

        // ---- scatter gates (D: col=lane&15, row=(lane>>4)*4+reg) to [q][col][17] ----
        #pragma unroll
        for (int reg = 0; reg < 4; ++reg) {
            gateL[(wid * 32 + cidx) * 17      + kh * 4 + reg] = acc0[reg];
            gateL[(wid * 32 + 16 + cidx) * 17 + kh * 4 + reg] = acc1[reg];
        }
        __syncthreads();

        // ---- eltwise LSTM cell for (er, eu) and (er, eu+16) ----
        const float xv = xrow[t];
        float g0[4], g1[4];
        #pragma unroll
        for (int q = 0; q < 4; ++q) {
            g0[q] = gateL[(q * 32 + eu) * 17 + er]      + xv * wx0[q] + bb0[q];
            g1[q] = gateL[(q * 32 + 16 + eu) * 17 + er] + xv * wx1[q] + bb1[q];
        }
        cc0 = fmaf(sigmoidf_(g0[2] + 1.0f), cc0, sigmoidf_(g0[0]) * tanhf_(g0[1]));
        const float h0 = sigmoidf_(g0[3]) * tanhf_(cc0);
        cc1 = fmaf(sigmoidf_(g1[2] + 1.0f), cc1, sigmoidf_(g1[0]) * tanhf_(g1[1]));
        const float h1 = sigmoidf_(g1[3]) * tanhf_(cc1);

        // ---- pack own h-chunk (A-frag order) and store ----
        const float h0n = __shfl_xor(h0, 1, 64);
        const float h1n = __shfl_xor(h1, 1, 64);
        if ((eu & 1) == 0) {
            const int bufw  = (t + 1) & 1;
            const int basew = ((bufw * NGRP + g) * NSLC + s) * 512 + er * 16;
            const uint32_t hi0 = bf16rne(h0),  hi0n = bf16rne(h0n);
            const uint32_t hi1 = bf16rne(h1),  hi1n = bf16rne(h1n);
            const uint32_t lo0  = bf16rne(h0  - bf16tof(hi0));
            const uint32_t lo0n = bf16rne(h0n - bf16tof(hi0n));
            const uint32_t lo1  = bf16rne(h1  - bf16tof(hi1));
            const uint32_t lo1n = bf16rne(h1n - bf16tof(hi1n));
            const int D0 = eu >> 1, D1 = 8 + (eu >> 1);
            __hip_atomic_store(&hx[basew + D0], hi0 | (hi0n << 16),
                               __ATOMIC_RELAXED, __HIP_MEMORY_SCOPE_AGENT);
            __hip_atomic_store(&hx[basew + D1], hi1 | (hi1n << 16),
                               __ATOMIC_RELAXED, __HIP_MEMORY_SCOPE_AGENT);
            __hip_atomic_store(&hx[basew + 256 + D0], lo0 | (lo0n << 16),
                               __ATOMIC_RELAXED, __HIP_MEMORY_SCOPE_AGENT);
            __hip_atomic_store(&hx[basew + 256 + D1], lo1 | (lo1n << 16),
                               __ATOMIC_RELAXED, __HIP_MEMORY_SCOPE_AGENT);
        }
        __syncthreads();   // drains vmcnt(0): chunk stores at coherent point
        if (tid == 0) {
            __hip_atomic_store(&tags[g * 8 + s], (uint32_t)(t + 1),
                               __ATOMIC_RELAXED, __HIP_MEMORY_SCOPE_AGENT);
        }
    }
}

// One block per batch row: dense = relu(h @ W_dense + b); logits = dense @ W_pred + b
__global__ __launch_bounds__(256, 1)
void head_kernel(const uint32_t* __restrict__ hx,
                 const float* __restrict__ W_dense,
                 const float* __restrict__ b_dense,
                 const float* __restrict__ W_pred,
                 const float* __restrict__ b_pred,
                 float* __restrict__ out) {
    __shared__ float hs[HID];
    __shared__ float ds[DNS];
    __shared__ float red[4];

    const int b = blockIdx.x;
    const int g = b >> 4, er = b & 15;
    const int tid = threadIdx.x;

    {   // reconstruct h = hi + lo from buf 0 chunk of (g, slice s)
        const int s  = tid >> 5;
        const int uu = tid & 31;
        const int base = (g * NSLC + s) * 512 + er * 16;
        const uint32_t dh = __hip_atomic_load(&hx[base + (uu >> 1)],
                                              __ATOMIC_RELAXED, __HIP_MEMORY_SCOPE_AGENT);
        const uint32_t dl = __hip_atomic_load(&hx[base + 256 + (uu >> 1)],
                                              __ATOMIC_RELAXED, __HIP_MEMORY_SCOPE_AGENT);
        const int sh = (uu & 1) * 16;
        hs[tid] = bf16tof((dh >> sh) & 0xFFFFu) + bf16tof((dl >> sh) & 0xFFFFu);
    }
    __syncthreads();

    for (int d = tid; d < DNS; d += 256) {
        float acc = b_dense[d];
        for (int k = 0; k < HID; k += 4) {
            float4 h4 = *reinterpret_cast<const float4*>(&hs[k]);
            acc = fmaf(h4.x, W_dense[(k + 0) * DNS + d], acc);
            acc = fmaf(h4.y, W_dense[(k + 1) * DNS + d], acc);
            acc = fmaf(h4.z, W_dense[(k + 2) * DNS + d], acc);
            acc = fmaf(h4.w, W_dense[(k + 3) * DNS + d], acc);
        }
        ds[d] = fmaxf(acc, 0.0f);
    }
    __syncthreads();

    const int wid = tid >> 6, lane = tid & 63;
    for (int c = 0; c < NCLS; ++c) {
        float p = 0.0f;
        for (int k = tid; k < DNS; k += 256) {
            p = fmaf(ds[k], W_pred[k * NCLS + c], p);
        }
        #pragma unroll
        for (int off = 32; off > 0; off >>= 1) {
            p += __shfl_down(p, off, 64);
        }
        if (lane == 0) red[wid] = p;
        __syncthreads();
        if (tid == 0) {
            out[b * NCLS + c] = red[0] + red[1] + red[2] + red[3] + b_pred[c];
        }
        __syncthreads();
    }
}

extern "C" void kernel_launch(void* const* d_in, const int* in_sizes, int n_in,
                              void* d_out, int out_size, void* d_ws, size_t ws_size,
                              hipStream_t stream) {
    const float* X       = (const float*)d_in[0];
    const float* W_lstm  = (const float*)d_in[1];
    const float* b_lstm  = (const float*)d_in[2];
    const float* W_dense = (const float*)d_in[3];
    const float* b_dense = (const float*)d_in[4];
    const float* W_pred  = (const float*)d_in[5];
    const float* b_pred  = (const float*)d_in[6];
    float* out = (float*)d_out;

    uint32_t* hx   = (uint32_t*)d_ws;                 // 131072 dwords = 512 KB
    uint32_t* tags = hx + 131072;                     // 128 dwords

    hipMemsetAsync(hx, 0, NGRP * NSLC * 512 * sizeof(uint32_t), stream);   // h_0 = 0 (buf 0)
    hipMemsetAsync(tags, 0, NGRP * NSLC * sizeof(uint32_t), stream);

    lstm_mfma3<<<NGRP * NSLC, 256, 0, stream>>>(X, W_lstm, b_lstm, hx, tags);
    head_kernel<<<BATCH, 256, 0, stream>>>(hx, W_dense, b_dense, W_pred, b_pred, out);
}

// Round 12
// 2400.934 us; speedup vs baseline: 2.0755x; 1.2059x over previous
//
#include <hip/hip_runtime.h>
#include <stdint.h>

#define TSEQ  784
#define BATCH 256
#define HID   256
#define DNS   1024
#define NCLS  10
#define NGRP  16   // groups (16 batch rows each)
#define NSLC  8    // slices (32 units x 4 gates = 128 gate-cols each)

typedef __attribute__((ext_vector_type(8))) short bf16x8_t;
typedef __attribute__((ext_vector_type(4))) float f32x4_t;

__device__ __forceinline__ float sigmoidf_(float x) { return 1.0f / (1.0f + __expf(-x)); }
__device__ __forceinline__ float tanhf_(float x) {
    float ax = fabsf(x);
    float e  = __expf(2.0f * ax);
    float r  = 1.0f - 2.0f / (e + 1.0f);
    return copysignf(r, x);
}
__device__ __forceinline__ uint32_t bf16rne(float f) {
    uint32_t u = __float_as_uint(f);
    return (u + 0x7FFFu + ((u >> 16) & 1u)) >> 16;
}
__device__ __forceinline__ float bf16tof(uint32_t h) { return __uint_as_float(h << 16); }

union AF { uint32_t u[4]; unsigned long long q[2]; bf16x8_t v; };

#define ALOAD(dst, ptr) \
    dst = __hip_atomic_load((ptr), __ATOMIC_RELAXED, __HIP_MEMORY_SCOPE_AGENT)

// 128 blocks = 16 groups x 8 slices, 256 threads (4 waves).
// K-PARTITIONED GEMM: wave w owns k-tiles {2w,2w+1}; loads ONLY its 4 KB of A
// directly from global (non-redundant, coalesced), computes partials for all
// 8 n-tiles, k-reduction via parts[] in LDS. No A staging, 3 barriers/step.
// Wh slice bf16 hi/lo in LDS; 3-term split MFMA (round-8 proven numerics).
__global__ __launch_bounds__(256, 1)
void lstm_mfma4(const float* __restrict__ X,
                const float* __restrict__ W_lstm,
                const float* __restrict__ b_lstm,
                uint32_t* __restrict__ hx,      // 2 bufs * 16 g * 8 s * 512 dwords
                uint32_t* __restrict__ tags)    // 128 monotonic tags [g*8+s]
{
    __shared__ uint32_t WtU[32768];                       // 128 KB weights hi/lo
    __shared__ __align__(16) float parts[32 * 256];       // 32 KB k-partial gates

    const int tid  = threadIdx.x;
    const int lane = tid & 63;
    const int wid  = tid >> 6;    // 0..3: owns k-tiles {2*wid, 2*wid+1}
    const int cidx = lane & 15;   // A row / B col / D col
    const int kh   = lane >> 4;   // 0..3 k-subgroup

    const int bid = blockIdx.x;
    const int s   = bid >> 4;     // slice 0..7
    const int g   = bid & 15;     // group 0..15 (8 slices share bid%8 -> XCD)

    // ---- one-time: stage Wh slice into LDS as bf16 hi/lo, chunk-XOR-swizzled ----
    for (int idx = tid; idx < 8 * 16 * 128; idx += 256) {
        const int n  = idx >> 11;          // n-tile 0..7
        const int c  = (idx >> 7) & 15;    // col within tile
        const int dw = idx & 127;          // k-pair index
        const int k0 = dw * 2;
        const int col = (n >> 1) * 256 + s * 32 + (n & 1) * 16 + c;
        const float w0 = W_lstm[(1 + k0) * 1024 + col];
        const float w1 = W_lstm[(2 + k0) * 1024 + col];
        const uint32_t h0 = bf16rne(w0), h1 = bf16rne(w1);
        const uint32_t l0 = bf16rne(w0 - bf16tof(h0));
        const uint32_t l1 = bf16rne(w1 - bf16tof(h1));
        const int kc = dw >> 2, rem = dw & 3;
        const int dwp = ((kc ^ (c & 7)) << 2) | rem;
        const int o = (n * 16 + c) * 128 + dwp;
        WtU[o]         = h0 | (h1 << 16);
        WtU[16384 + o] = l0 | (l1 << 16);
    }

    // eltwise mapping (TRANSPOSED vs r8 for conflict-free parts reads):
    // er = batch row = tid&15, eu = unit = tid>>4; cells (er,eu),(er,eu+16)
    const int er = tid & 15;
    const int eu = tid >> 4;
    float wx0[4], wx1[4], bb0[4], bb1[4];
    #pragma unroll
    for (int q = 0; q < 4; ++q) {
        const int c0 = q * 256 + s * 32 + eu;
        wx0[q] = W_lstm[c0];      wx1[q] = W_lstm[c0 + 16];
        bb0[q] = b_lstm[c0];      bb1[q] = b_lstm[c0 + 16];
    }
    const float* xrow = X + (g * 16 + er) * TSEQ;
    float cc0 = 0.0f, cc1 = 0.0f;

    __syncthreads();

    for (int t = 0; t < TSEQ; ++t) {
        // ---- wave 0 polls all 8 producer tags >= t ----
        if (t > 0 && wid == 0) {
            const uint32_t tt = (uint32_t)t;
            int guard = 1 << 22;
            bool ok;
            do {
                uint32_t v = __hip_atomic_load(&tags[g * 8 + (lane & 7)],
                                               __ATOMIC_RELAXED, __HIP_MEMORY_SCOPE_AGENT);
                ok = __all(v >= tt);
            } while (!ok && --guard);
        }
        __syncthreads();   // join + fence: A-loads cannot hoist above poll

        // ---- this wave's A-fragments (2 k-tiles, hi+lo) direct from global ----
        const int bufr = t & 1;
        AF ah[2], al[2];
        #pragma unroll
        for (int ktl = 0; ktl < 2; ++ktl) {
            const int kt = wid * 2 + ktl;
            const int base = ((bufr * NGRP + g) * NSLC + kt) * 512 + cidx * 16 + kh * 4;
            const unsigned long long* pa = (const unsigned long long*)&hx[base];
            ALOAD(ah[ktl].q[0], pa);       ALOAD(ah[ktl].q[1], pa + 1);
            ALOAD(al[ktl].q[0], pa + 128); ALOAD(al[ktl].q[1], pa + 129);
        }

        // ---- GEMM: 3-term split, this wave's 2 k-tiles x all 8 n-tiles ----
        f32x4_t acc[8];
        #pragma unroll
        for (int n = 0; n < 8; ++n) acc[n] = (f32x4_t){0.f, 0.f, 0.f, 0.f};

        #pragma unroll
        for (int ktl = 0; ktl < 2; ++ktl) {
            const int kc  = (wid * 2 + ktl) * 4 + kh;
            const int swz = (kc ^ (cidx & 7)) << 2;
            #pragma unroll
            for (int n = 0; n < 8; ++n) {
                const int ob = (n * 16 + cidx) * 128 + swz;
                bf16x8_t bh = *reinterpret_cast<const bf16x8_t*>(&WtU[ob]);
                bf16x8_t bl = *reinterpret_cast<const bf16x8_t*>(&WtU[16384 + ob]);
                acc[n] = __builtin_amdgcn_mfma_f32_16x16x32_bf16(ah[ktl].v, bh, acc[n], 0, 0, 0);
                acc[n] = __builtin_amdgcn_mfma_f32_16x16x32_bf16(ah[ktl].v, bl, acc[n], 0, 0, 0);
                acc[n] = __builtin_amdgcn_mfma_f32_16x16x32_bf16(al[ktl].v, bh, acc[n], 0, 0, 0);
            }
        }

        // ---- write k-partials (D: col=cidx, row=kh*4+reg) to parts[wid*8+n] ----
        #pragma unroll
        for (int n = 0; n < 8; ++n) {
            *reinterpret_cast<f32x4_t*>(
                &parts[(wid * 8 + n) * 256 + cidx * 16 + kh * 4]) = acc[n];
        }
        __syncthreads();

        // ---- eltwise: sum 4 wave-partials per gate, cells (er,eu),(er,eu+16) ----
        const float xv = xrow[t];
        float g0[4], g1[4];
        #pragma unroll
        for (int q = 0; q < 4; ++q) {
            float s0 = 0.f, s1 = 0.f;
            #pragma unroll
            for (int w = 0; w < 4; ++w) {
                s0 += parts[(w * 8 + 2 * q)     * 256 + eu * 16 + er];
                s1 += parts[(w * 8 + 2 * q + 1) * 256 + eu * 16 + er];
            }
            g0[q] = s0 + xv * wx0[q] + bb0[q];
            g1[q] = s1 + xv * wx1[q] + bb1[q];
        }
        cc0 = fmaf(sigmoidf_(g0[2] + 1.0f), cc0, sigmoidf_(g0[0]) * tanhf_(g0[1]));
        const float h0 = sigmoidf_(g0[3]) * tanhf_(cc0);
        cc1 = fmaf(sigmoidf_(g1[2] + 1.0f), cc1, sigmoidf_(g1[0]) * tanhf_(g1[1]));
        const float h1 = sigmoidf_(g1[3]) * tanhf_(cc1);

        // ---- pack own h-chunk (A-frag order); neighbor unit eu^1 is lane^16 ----
        const float h0n = __shfl_xor(h0, 16, 64);
        const float h1n = __shfl_xor(h1, 16, 64);
        if ((eu & 1) == 0) {
            const int bufw  = (t + 1) & 1;
            const int basew = ((bufw * NGRP + g) * NSLC + s) * 512 + er * 16;
            const uint32_t hi0 = bf16rne(h0),  hi0n = bf16rne(h0n);
            const uint32_t hi1 = bf16rne(h1),  hi1n = bf16rne(h1n);
            const uint32_t lo0  = bf16rne(h0  - bf16tof(hi0));
            const uint32_t lo0n = bf16rne(h0n - bf16tof(hi0n));
            const uint32_t lo1  = bf16rne(h1  - bf16tof(hi1));
            const uint32_t lo1n = bf16rne(h1n - bf16tof(hi1n));
            const int D0 = eu >> 1, D1 = 8 + (eu >> 1);
            __hip_atomic_store(&hx[basew + D0], hi0 | (hi0n << 16),
                               __ATOMIC_RELAXED, __HIP_MEMORY_SCOPE_AGENT);
            __hip_atomic_store(&hx[basew + D1], hi1 | (hi1n << 16),
                               __ATOMIC_RELAXED, __HIP_MEMORY_SCOPE_AGENT);
            __hip_atomic_store(&hx[basew + 256 + D0], lo0 | (lo0n << 16),
                               __ATOMIC_RELAXED, __HIP_MEMORY_SCOPE_AGENT);
            __hip_atomic_store(&hx[basew + 256 + D1], lo1 | (lo1n << 16),
                               __ATOMIC_RELAXED, __HIP_MEMORY_SCOPE_AGENT);
        }
        __syncthreads();   // drains vmcnt(0): chunk stores at coherent point
        if (tid == 0) {
            __hip_atomic_store(&tags[g * 8 + s], (uint32_t)(t + 1),
                               __ATOMIC_RELAXED, __HIP_MEMORY_SCOPE_AGENT);
        }
    }
}

// One block per batch row: dense = relu(h @ W_dense + b); logits = dense @ W_pred + b
__global__ __launch_bounds__(256, 1)
void head_kernel(const uint32_t* __restrict__ hx,
                 const float* __restrict__ W_dense,
                 const float* __restrict__ b_dense,
                 const float* __restrict__ W_pred,
                 const float* __restrict__ b_pred,
                 float* __restrict__ out) {
    __shared__ float hs[HID];
    __shared__ float ds[DNS];
    __shared__ float red[4];

    const int b = blockIdx.x;
    const int g = b >> 4, er = b & 15;
    const int tid = threadIdx.x;

    {   // reconstruct h = hi + lo from buf 0 chunk of (g, slice s)
        const int s  = tid >> 5;
        const int uu = tid & 31;
        const int base = (g * NSLC + s) * 512 + er * 16;
        const uint32_t dh = __hip_atomic_load(&hx[base + (uu >> 1)],
                                              __ATOMIC_RELAXED, __HIP_MEMORY_SCOPE_AGENT);
        const uint32_t dl = __hip_atomic_load(&hx[base + 256 + (uu >> 1)],
                                              __ATOMIC_RELAXED, __HIP_MEMORY_SCOPE_AGENT);
        const int sh = (uu & 1) * 16;
        hs[tid] = bf16tof((dh >> sh) & 0xFFFFu) + bf16tof((dl >> sh) & 0xFFFFu);
    }
    __syncthreads();

    for (int d = tid; d < DNS; d += 256) {
        float acc = b_dense[d];
        for (int k = 0; k < HID; k += 4) {
            float4 h4 = *reinterpret_cast<const float4*>(&hs[k]);
            acc = fmaf(h4.x, W_dense[(k + 0) * DNS + d], acc);
            acc = fmaf(h4.y, W_dense[(k + 1) * DNS + d], acc);
            acc = fmaf(h4.z, W_dense[(k + 2) * DNS + d], acc);
            acc = fmaf(h4.w, W_dense[(k + 3) * DNS + d], acc);
        }
        ds[d] = fmaxf(acc, 0.0f);
    }
    __syncthreads();

    const int wid = tid >> 6, lane = tid & 63;
    for (int c = 0; c < NCLS; ++c) {
        float p = 0.0f;
        for (int k = tid; k < DNS; k += 256) {
            p = fmaf(ds[k], W_pred[k * NCLS + c], p);
        }
        #pragma unroll
        for (int off = 32; off > 0; off >>= 1) {
            p += __shfl_down(p, off, 64);
        }
        if (lane == 0) red[wid] = p;
        __syncthreads();
        if (tid == 0) {
            out[b * NCLS + c] = red[0] + red[1] + red[2] + red[3] + b_pred[c];
        }
        __syncthreads();
    }
}

extern "C" void kernel_launch(void* const* d_in, const int* in_sizes, int n_in,
                              void* d_out, int out_size, void* d_ws, size_t ws_size,
                              hipStream_t stream) {
    const float* X       = (const float*)d_in[0];
    const float* W_lstm  = (const float*)d_in[1];
    const float* b_lstm  = (const float*)d_in[2];
    const float* W_dense = (const float*)d_in[3];
    const float* b_dense = (const float*)d_in[4];
    const float* W_pred  = (const float*)d_in[5];
    const float* b_pred  = (const float*)d_in[6];
    float* out = (float*)d_out;

    uint32_t* hx   = (uint32_t*)d_ws;                 // 131072 dwords = 512 KB
    uint32_t* tags = hx + 131072;                     // 128 dwords

    hipMemsetAsync(hx, 0, NGRP * NSLC * 512 * sizeof(uint32_t), stream);   // h_0 = 0 (buf 0)
    hipMemsetAsync(tags, 0, NGRP * NSLC * sizeof(uint32_t), stream);

    lstm_mfma4<<<NGRP * NSLC, 256, 0, stream>>>(X, W_lstm, b_lstm, hx, tags);
    head_kernel<<<BATCH, 256, 0, stream>>>(hx, W_dense, b_dense, W_pred, b_pred, out);
}